// Round 13
// baseline (10414.502 us; speedup 1.0000x reference)
//
#include <hip/hip_runtime.h>

#define B_ROWS 8192
#define UNITS 512
#define NITER 25
#define INSZ 176
#define KPAD 128
#define GRAD_COLS 101

typedef __attribute__((ext_vector_type(8))) short short8;
typedef __attribute__((ext_vector_type(4))) float f32x4;
typedef __attribute__((ext_vector_type(8))) _Float16 half8;

__device__ __forceinline__ unsigned short f2h_bits(float f) {
  _Float16 h = (_Float16)f;
  return __builtin_bit_cast(unsigned short, h);
}
__device__ __forceinline__ float h2f_bits(unsigned short b) {
  return (float)__builtin_bit_cast(_Float16, b);
}
__device__ __forceinline__ float fast_tanh(float x) {
  float e = __expf(2.0f * x);
  return 1.0f - 2.0f / (e + 1.0f);
}

typedef __attribute__((address_space(3))) unsigned int lds_u32;
typedef __attribute__((address_space(1))) const unsigned int glb_u32;
__device__ __forceinline__ void gload16(const void* g, void* l) {
  __builtin_amdgcn_global_load_lds((glb_u32*)g, (lds_u32*)l, 16, 0, 0);
}

__device__ __forceinline__ f32x4 mf(short8 a, short8 b, f32x4 c) {
  return __builtin_amdgcn_mfma_f32_16x16x32_f16(
      __builtin_bit_cast(half8, a), __builtin_bit_cast(half8, b), c, 0, 0, 0);
}

struct MP {
  const unsigned short *TW0, *TW1, *TW2, *TW3, *CW0, *CW1, *CW2, *CW3;
  unsigned short *H0, *H1, *H2, *U3, *Ub, *Uc;
  const float *x, *b0, *b1, *b2, *b3, *W4, *b4;
  float *w_acc, *w_out, *grad;
  unsigned *cnt;
};

// ---------------------------------------------------------------------------
// Weight prep + zero w_acc + zero panel counters (every call: replay-safe).
// ---------------------------------------------------------------------------
__global__ __launch_bounds__(256)
void prep_kernel(const float* __restrict__ W0, const float* __restrict__ W1,
                 const float* __restrict__ W2, const float* __restrict__ W3,
                 unsigned short* TW0, unsigned short* TW1,
                 unsigned short* TW2, unsigned short* TW3,
                 unsigned short* CW0, unsigned short* CW1,
                 unsigned short* CW2, unsigned short* CW3,
                 float* w_acc, unsigned* cnt)
{
  int id = blockIdx.x * 256 + threadIdx.x;
  if (id < 128) cnt[id] = 0u;
  if (id < NITER * B_ROWS) w_acc[id] = 0.0f;
  if (id < 512 * KPAD) {
    int n = id >> 7, k = id & (KPAD - 1);
    TW0[id] = f2h_bits((k < 101) ? W0[(size_t)k * 512 + n] : 0.0f);
    int n2 = id >> 9, k2 = id & 511;
    CW0[id] = f2h_bits((n2 < 101) ? W0[(size_t)n2 * 512 + k2] : 0.0f);
  }
  {
    int n = id >> 9, k = id & 511;
    TW1[id] = f2h_bits(W1[(size_t)k * 512 + n]);
    TW2[id] = f2h_bits(W2[(size_t)k * 512 + n]);
    TW3[id] = f2h_bits(W3[(size_t)k * 512 + n]);
    CW1[id] = f2h_bits(W1[id]);
    CW2[id] = f2h_bits(W2[id]);
    CW3[id] = f2h_bits(W3[id]);
  }
}

// ---------------------------------------------------------------------------
// Panel GEMM: C[64 x NT] = A[panel rows x K] @ Bt[NT x K], fp16.
// 4 waves (2m x 2n), BK=64, counted-vmcnt 2-barrier pipeline (replay-proven).
// NT=128 (normal stages) or NT=32 (gr0 N-split). Bt is pre-offset to the
// worker's N-tile base; ncol0 = bn*NT gives global output columns.
// EPI 0: tanh(acc+bias) -> Oh        EPI 1: acc*(1-h^2) (h from Hh) -> Oh
// EPI 2: grad store (n<101)          EPI 3: U3 + w-dot atomicAdd w_acc
// EPI 4: f0 with on-the-fly D built in LDS from x / w_out / w_acc.
// ---------------------------------------------------------------------------
template<int EPI, int NT>
__device__ __forceinline__ void gemm_panel(
    short* smem, int panel, int bn,
    const unsigned short* A, const unsigned short* Bt, int K,
    const float* bias, const unsigned short* Hh, unsigned short* Oh,
    float* Og, int iter,
    const float* W4p, const float* xp, float* woutp,
    const float* waccp, const float* b4p)
{
  const int t = threadIdx.x;
  const int w = t >> 6;
  const int lane = t & 63;
  const int l15 = lane & 15, l4 = lane >> 4;
  constexpr int NB = NT / 32;           // B staging rounds / bh frag count
  const int wm = (w >> 1) * 32;
  const int wn = (w & 1) * (NT / 2);
  const int ncol0 = bn * NT;
  const int NK = K >> 6;
  const int row0 = panel * 64;
  f32x4 acc[2][NB] = {};

  const int sr = t >> 3;   // 0..31
  const int ss = t & 7;

  if constexpr (EPI == 4) {
    // build the 64x128 D tile in LDS (two 4096-short K-halves at smem[0..8192))
    const int i = iter;
#pragma unroll
    for (int q = 0; q < 2; ++q) {
      int r = q * 32 + sr;
      int b = row0 + r;
      float wv = (i > 0) ? (waccp[b] + b4p[0]) : 0.0f;
      if (i > 0 && ss == 0 && bn == 0)
        woutp[(size_t)b * NITER + (i - 1)] = wv;
      int cc = (ss ^ (r & 7)) << 3;
#pragma unroll
      for (int half = 0; half < 2; ++half) {
        short8 vals;
#pragma unroll
        for (int j = 0; j < 8; ++j) {
          int col = half * 64 + cc + j;
          float val;
          if (col < 25 - i)       val = xp[(size_t)b * INSZ + i + col];
          else if (col < 24)      val = woutp[(size_t)b * NITER + (col - (25 - i))];
          else if (col == 24)     val = wv;
          else if (col < 100)     val = xp[(size_t)b * INSZ + 26 + 3 * i + (col - 25)];
          else if (col == 100)    val = (float)i;
          else                    val = 0.0f;
          vals[j] = (short)f2h_bits(val);
        }
        *(short8*)&smem[half * 4096 + r * 64 + ss * 8] = vals;
      }
    }
  }

  auto stage = [&](int ks, int buf) {
    int kc = ks << 6;
    if constexpr (EPI == 4) {
      short* Bs = smem + 8192 + buf * 8192;
#pragma unroll
      for (int q = 0; q < NB; ++q) {
        int r = q * 32 + sr;
        int c = ss ^ (r & 7);
        gload16(Bt + (size_t)r * K + kc + c * 8, &Bs[q * 2048 + w * 512]);
      }
    } else {
      short* As = smem + buf * 12288;
      short* Bs = As + 4096;
#pragma unroll
      for (int q = 0; q < 2; ++q) {
        int r = q * 32 + sr;
        int c = ss ^ (r & 7);
        gload16(A + (size_t)(row0 + r) * K + kc + c * 8, &As[q * 2048 + w * 512]);
      }
#pragma unroll
      for (int q = 0; q < NB; ++q) {
        int r = q * 32 + sr;
        int c = ss ^ (r & 7);
        gload16(Bt + (size_t)r * K + kc + c * 8, &Bs[q * 2048 + w * 512]);
      }
    }
  };

  stage(0, 0);
  for (int ks = 0; ks < NK; ++ks) {
    if (ks + 1 < NK) {
      stage(ks + 1, (ks + 1) & 1);
      if constexpr (EPI == 4)       asm volatile("s_waitcnt vmcnt(4)" ::: "memory");
      else if constexpr (NT == 128) asm volatile("s_waitcnt vmcnt(6)" ::: "memory");
      else                          asm volatile("s_waitcnt vmcnt(3)" ::: "memory");
    } else {
      asm volatile("s_waitcnt vmcnt(0)" ::: "memory");
    }
    asm volatile("s_waitcnt lgkmcnt(0)" ::: "memory");  // EPI4: A-build visible
    __builtin_amdgcn_sched_barrier(0);
    __builtin_amdgcn_s_barrier();

    const short* As = (EPI == 4) ? (smem + ks * 4096) : (smem + (ks & 1) * 12288);
    const short* Bs = (EPI == 4) ? (smem + 8192 + (ks & 1) * 8192) : (As + 4096);
#pragma unroll
    for (int kk = 0; kk < 2; ++kk) {
      short8 av[2], bh[NB];
#pragma unroll
      for (int mi = 0; mi < 2; ++mi) {
        int row = wm + mi * 16 + l15;
        av[mi] = *(const short8*)&As[row * 64 + (((kk * 4 + l4) ^ (row & 7)) << 3)];
      }
#pragma unroll
      for (int ni = 0; ni < NB; ++ni) {
        int row = wn + ni * 16 + l15;
        bh[ni] = *(const short8*)&Bs[row * 64 + (((kk * 4 + l4) ^ (row & 7)) << 3)];
      }
#pragma unroll
      for (int mi = 0; mi < 2; ++mi)
#pragma unroll
        for (int ni = 0; ni < NB; ++ni)
          acc[mi][ni] = mf(av[mi], bh[ni], acc[mi][ni]);
    }
    asm volatile("s_waitcnt lgkmcnt(0)" ::: "memory");
    __builtin_amdgcn_sched_barrier(0);
    __builtin_amdgcn_s_barrier();
  }

  const int gm0 = row0 + wm;
  const int gn0 = ncol0 + wn;
  float wp[2][4] = {};
#pragma unroll
  for (int mi = 0; mi < 2; ++mi) {
#pragma unroll
    for (int ni = 0; ni < NB; ++ni) {
      int n = gn0 + ni * 16 + l15;
#pragma unroll
      for (int r = 0; r < 4; ++r) {
        int m = gm0 + mi * 16 + l4 * 4 + r;
        float v = acc[mi][ni][r];
        if constexpr (EPI == 0 || EPI == 4) {
          float h = fast_tanh(v + bias[n]);
          Oh[(size_t)m * UNITS + n] = f2h_bits(h);
        } else if constexpr (EPI == 1) {
          size_t idx = (size_t)m * UNITS + n;
          float h = h2f_bits(Hh[idx]);
          Oh[idx] = f2h_bits(v * (1.0f - h * h));
        } else if constexpr (EPI == 2) {
          if (n < GRAD_COLS)
            Og[((size_t)m * NITER + iter) * GRAD_COLS + n] = v;
        } else {
          float h = fast_tanh(v + bias[n]);
          float w4 = W4p[n];
          Oh[(size_t)m * UNITS + n] = f2h_bits((1.0f - h * h) * w4);
          wp[mi][r] += h * w4;
        }
      }
    }
  }
  if constexpr (EPI == 3) {
#pragma unroll
    for (int mi = 0; mi < 2; ++mi)
#pragma unroll
      for (int r = 0; r < 4; ++r) {
        float v = wp[mi][r];
        v += __shfl_xor(v, 1); v += __shfl_xor(v, 2);
        v += __shfl_xor(v, 4); v += __shfl_xor(v, 8);
        if (l15 == 0) {
          int m = gm0 + mi * 16 + l4 * 4 + r;
          atomicAdd(&Og[m], v);
        }
      }
  }
}

// ---------------------------------------------------------------------------
// Persistent megakernel: 512 workers = 128 panels x 4 N-owners; 200 stages;
// panel-local counter sync (spin relaxed, acquire on exit, release add).
// All 512 blocks resident by construction (48KB LDS + launch_bounds(256,2)
// -> 2 blocks/CU x 256 CUs). blockIdx%8 co-location is perf-only.
// ---------------------------------------------------------------------------
__global__ __launch_bounds__(256, 2)
void mega_kernel(MP mp)
{
  __shared__ short smem[24576];        // 48 KB
  const int xcd  = blockIdx.x & 7;
  const int slot = blockIdx.x >> 3;    // 0..63
  const int panel = xcd + 8 * (slot >> 2);   // 0..127
  const int bn = slot & 3;
  unsigned* cp = mp.cnt + panel;

  for (int s = 0; s < NITER * 8; ++s) {
    const int i = s >> 3, k = s & 7;
    if (s > 0) {
      if (threadIdx.x == 0) {
        const unsigned tgt = 4u * (unsigned)s;
        while (__hip_atomic_load(cp, __ATOMIC_RELAXED, __HIP_MEMORY_SCOPE_AGENT) < tgt)
          __builtin_amdgcn_s_sleep(16);
        (void)__hip_atomic_load(cp, __ATOMIC_ACQUIRE, __HIP_MEMORY_SCOPE_AGENT);
      }
      __syncthreads();
    }

    switch (k) {
      case 0:
        gemm_panel<4, 128>(smem, panel, bn, nullptr,
            mp.TW0 + (size_t)bn * 128 * KPAD, KPAD, mp.b0, nullptr, mp.H0,
            nullptr, i, nullptr, mp.x, mp.w_out,
            (i > 0) ? (mp.w_acc + (size_t)(i - 1) * B_ROWS) : mp.w_acc, mp.b4);
        break;
      case 1:
        gemm_panel<0, 128>(smem, panel, bn, mp.H0,
            mp.TW1 + (size_t)bn * 128 * 512, 512, mp.b1, nullptr, mp.H1,
            nullptr, i, nullptr, nullptr, nullptr, nullptr, nullptr);
        break;
      case 2:
        gemm_panel<0, 128>(smem, panel, bn, mp.H1,
            mp.TW2 + (size_t)bn * 128 * 512, 512, mp.b2, nullptr, mp.H2,
            nullptr, i, nullptr, nullptr, nullptr, nullptr, nullptr);
        break;
      case 3:
        gemm_panel<3, 128>(smem, panel, bn, mp.H2,
            mp.TW3 + (size_t)bn * 128 * 512, 512, mp.b3, nullptr, mp.U3,
            mp.w_acc + (size_t)i * B_ROWS, i, mp.W4, nullptr, nullptr, nullptr, nullptr);
        break;
      case 4:
        gemm_panel<1, 128>(smem, panel, bn, mp.U3,
            mp.CW3 + (size_t)bn * 128 * 512, 512, nullptr, mp.H2, mp.Ub,
            nullptr, i, nullptr, nullptr, nullptr, nullptr, nullptr);
        break;
      case 5:
        gemm_panel<1, 128>(smem, panel, bn, mp.Ub,
            mp.CW2 + (size_t)bn * 128 * 512, 512, nullptr, mp.H1, mp.Uc,
            nullptr, i, nullptr, nullptr, nullptr, nullptr, nullptr);
        break;
      case 6:
        gemm_panel<1, 128>(smem, panel, bn, mp.Uc,
            mp.CW1 + (size_t)bn * 128 * 512, 512, nullptr, mp.H0, mp.Ub,
            nullptr, i, nullptr, nullptr, nullptr, nullptr, nullptr);
        break;
      case 7:
        gemm_panel<2, 32>(smem, panel, bn, mp.Ub,
            mp.CW0 + (size_t)bn * 32 * 512, 512, nullptr, nullptr, nullptr,
            mp.grad, i, nullptr, nullptr, nullptr, nullptr, nullptr);
        if (i == NITER - 1 && bn == 0 && threadIdx.x < 64) {
          int m = panel * 64 + threadIdx.x;
          mp.w_out[(size_t)m * NITER + 24] =
              mp.w_acc[(size_t)24 * B_ROWS + m] + mp.b4[0];
        }
        break;
    }

    __syncthreads();   // all lanes done; vmcnt/lgkm drained (stores retired)
    if (threadIdx.x == 0)
      __hip_atomic_fetch_add(cp, 1u, __ATOMIC_RELEASE, __HIP_MEMORY_SCOPE_AGENT);
  }
}

// ---------------------------------------------------------------------------
extern "C" void kernel_launch(void* const* d_in, const int* in_sizes, int n_in,
                              void* d_out, int out_size, void* d_ws, size_t ws_size,
                              hipStream_t stream) {
  const float* x  = (const float*)d_in[0];
  const float* W0 = (const float*)d_in[1];
  const float* b0 = (const float*)d_in[2];
  const float* W1 = (const float*)d_in[3];
  const float* b1 = (const float*)d_in[4];
  const float* W2 = (const float*)d_in[5];
  const float* b2 = (const float*)d_in[6];
  const float* W3 = (const float*)d_in[7];
  const float* b3 = (const float*)d_in[8];
  const float* W4 = (const float*)d_in[9];
  const float* b4 = (const float*)d_in[10];

  float* w_out    = (float*)d_out;                              // (8192, 25)
  float* grad_out = (float*)d_out + (size_t)B_ROWS * NITER;     // (8192, 25, 101)

  char* p = (char*)d_ws;
  auto alloc = [&](size_t elems) { unsigned short* r = (unsigned short*)p; p += elems * 2; return r; };

  unsigned short* TW0 = alloc(512 * KPAD);
  unsigned short* TW1 = alloc(512 * 512);
  unsigned short* TW2 = alloc(512 * 512);
  unsigned short* TW3 = alloc(512 * 512);
  unsigned short* CW0 = alloc(KPAD * 512);
  unsigned short* CW1 = alloc(512 * 512);
  unsigned short* CW2 = alloc(512 * 512);
  unsigned short* CW3 = alloc(512 * 512);
  float* w_acc = (float*)p; p += (size_t)NITER * B_ROWS * 4;
  unsigned* cnt = (unsigned*)p; p += 128 * sizeof(unsigned);
  p = (char*)(((uintptr_t)p + 255) & ~(uintptr_t)255);

  const size_t SL = (size_t)B_ROWS * UNITS;
  unsigned short* H0 = alloc(SL);
  unsigned short* H1 = alloc(SL);
  unsigned short* H2 = alloc(SL);
  unsigned short* U3 = alloc(SL);
  unsigned short* Ub = alloc(SL);
  unsigned short* Uc = alloc(SL);

  prep_kernel<<<1024, 256, 0, stream>>>(W0, W1, W2, W3,
      TW0, TW1, TW2, TW3, CW0, CW1, CW2, CW3, w_acc, cnt);

  MP mp;
  mp.TW0 = TW0; mp.TW1 = TW1; mp.TW2 = TW2; mp.TW3 = TW3;
  mp.CW0 = CW0; mp.CW1 = CW1; mp.CW2 = CW2; mp.CW3 = CW3;
  mp.H0 = H0; mp.H1 = H1; mp.H2 = H2; mp.U3 = U3; mp.Ub = Ub; mp.Uc = Uc;
  mp.x = x; mp.b0 = b0; mp.b1 = b1; mp.b2 = b2; mp.b3 = b3;
  mp.W4 = W4; mp.b4 = b4;
  mp.w_acc = w_acc; mp.w_out = w_out; mp.grad = grad_out;
  mp.cnt = cnt;

  mega_kernel<<<512, 256, 0, stream>>>(mp);

  (void)in_sizes; (void)n_in; (void)out_size; (void)ws_size;
}

// Round 14
// 1892.750 us; speedup vs baseline: 5.5023x; 5.5023x over previous
//
#include <hip/hip_runtime.h>

#define B_ROWS 8192
#define UNITS 512
#define NITER 25
#define INSZ 176
#define KPAD 128
#define GRAD_COLS 101

typedef __attribute__((ext_vector_type(8))) short short8;
typedef __attribute__((ext_vector_type(4))) float f32x4;
typedef __attribute__((ext_vector_type(8))) _Float16 half8;

__device__ __forceinline__ unsigned short f2h_bits(float f) {
  _Float16 h = (_Float16)f;
  return __builtin_bit_cast(unsigned short, h);
}
__device__ __forceinline__ float h2f_bits(unsigned short b) {
  return (float)__builtin_bit_cast(_Float16, b);
}
__device__ __forceinline__ float fast_tanh(float x) {
  float e = __expf(2.0f * x);
  return 1.0f - 2.0f / (e + 1.0f);
}

typedef __attribute__((address_space(3))) unsigned int lds_u32;
typedef __attribute__((address_space(1))) const unsigned int glb_u32;
__device__ __forceinline__ void gload16(const void* g, void* l) {
  __builtin_amdgcn_global_load_lds((glb_u32*)g, (lds_u32*)l, 16, 0, 0);
}

__device__ __forceinline__ f32x4 mf(short8 a, short8 b, f32x4 c) {
  return __builtin_amdgcn_mfma_f32_16x16x32_f16(
      __builtin_bit_cast(half8, a), __builtin_bit_cast(half8, b), c, 0, 0, 0);
}

struct GArgs {
  const unsigned short *A;            // activations plane, M x K (EPI != 4)
  const unsigned short *B;            // weights plane, N x K (n-major)
  int K;
  const float* bias;
  const unsigned short *Hh;           // EPI1: fwd activations
  unsigned short *Oh;                 // output plane (fp16)
  float* Og;                          // EPI2: grad out; EPI3: w_acc slice
  int iter;                           // EPI2: iter; EPI4: iteration i
  const float* W4p;                   // EPI3
  const float* xp;                    // EPI4
  float* woutp;                       // EPI4: writes col iter-1; EPI2-final: col 24
  const float* waccp;                 // EPI4: w_acc row (iter-1); EPI2-final: row 24
  const float* b4p;                   // EPI4 / EPI2-final
};

// ---------------------------------------------------------------------------
// Weight prep: fp16 planes, n-major layouts, zero-padded. Zeroes w_acc
// (required every call: EPI3 accumulates into it; harness replays).
// ---------------------------------------------------------------------------
__global__ __launch_bounds__(256)
void prep_kernel(const float* __restrict__ W0, const float* __restrict__ W1,
                 const float* __restrict__ W2, const float* __restrict__ W3,
                 unsigned short* TW0, unsigned short* TW1,
                 unsigned short* TW2, unsigned short* TW3,
                 unsigned short* CW0, unsigned short* CW1,
                 unsigned short* CW2, unsigned short* CW3,
                 float* w_acc)
{
  int id = blockIdx.x * 256 + threadIdx.x;
  if (id < NITER * B_ROWS) w_acc[id] = 0.0f;
  if (id < 512 * KPAD) {
    int n = id >> 7, k = id & (KPAD - 1);
    TW0[id] = f2h_bits((k < 101) ? W0[(size_t)k * 512 + n] : 0.0f);
    int n2 = id >> 9, k2 = id & 511;
    CW0[id] = f2h_bits((n2 < 101) ? W0[(size_t)n2 * 512 + k2] : 0.0f);
  }
  {
    int n = id >> 9, k = id & 511;
    TW1[id] = f2h_bits(W1[(size_t)k * 512 + n]);
    TW2[id] = f2h_bits(W2[(size_t)k * 512 + n]);
    TW3[id] = f2h_bits(W3[(size_t)k * 512 + n]);
    CW1[id] = f2h_bits(W1[id]);
    CW2[id] = f2h_bits(W2[id]);
    CW3[id] = f2h_bits(W3[id]);
  }
}

// ---------------------------------------------------------------------------
// Unified GEMM body: 64x128 tile, BK=64, 4 waves, 48KB LDS, 3 blocks/CU.
// Counted-vmcnt 2-barrier pipeline (replay-verified rounds 5-12).
// EPI 0: tanh(acc+bias) -> Oh
// EPI 1: acc*(1-h^2), h from Hh -> Oh
// EPI 2: grad store (bm=id grid, n<101); optional final w_out[:,24] write
// EPI 3: h=tanh(acc+bias); Oh=(1-h^2)*W4[n]; w-dot -> atomicAdd w_acc
// EPI 4: f0 with on-the-fly D built in LDS from x/w_out/w_acc; also writes
//        w_out[:, iter-1] (bn==0, ss==0 lanes).
// ---------------------------------------------------------------------------
template<int EPI>
__device__ __forceinline__ void gemm64(const GArgs g, short* smem, int id)
{
  const int t = threadIdx.x;
  const int w = t >> 6;
  const int lane = t & 63;
  const int l15 = lane & 15, l4 = lane >> 4;
  const int bm = (EPI == 2) ? id : ((id & 7) | ((id >> 5) << 3));
  const int bn = (EPI == 2) ? 0  : ((id >> 3) & 3);
  const int wm = (w >> 1) * 32, wn = (w & 1) * 64;
  const int K = g.K;
  const int NK = K >> 6;
  f32x4 acc[2][4] = {};

  const int sr = t >> 3;   // 0..31
  const int ss = t & 7;

  if constexpr (EPI == 4) {
    // build the 64x128 D tile in LDS (two 4096-short K-halves at smem[0..8192))
    const int i = g.iter;
#pragma unroll
    for (int q = 0; q < 2; ++q) {
      int r = q * 32 + sr;
      int b = bm * 64 + r;
      float wv = (i > 0) ? (g.waccp[b] + g.b4p[0]) : 0.0f;
      if (i > 0 && ss == 0 && bn == 0)
        g.woutp[(size_t)b * NITER + (i - 1)] = wv;
      int cc = (ss ^ (r & 7)) << 3;            // global col base for this slot
#pragma unroll
      for (int half = 0; half < 2; ++half) {
        short8 vals;
#pragma unroll
        for (int j = 0; j < 8; ++j) {
          int col = half * 64 + cc + j;
          float val;
          if (col < 25 - i)       val = g.xp[(size_t)b * INSZ + i + col];
          else if (col < 24)      val = g.woutp[(size_t)b * NITER + (col - (25 - i))];
          else if (col == 24)     val = wv;
          else if (col < 100)     val = g.xp[(size_t)b * INSZ + 26 + 3 * i + (col - 25)];
          else if (col == 100)    val = (float)i;
          else                    val = 0.0f;
          vals[j] = (short)f2h_bits(val);
        }
        *(short8*)&smem[half * 4096 + r * 64 + ss * 8] = vals;
      }
    }
  }

  // stage: EPI4 -> B only (4 gloads, bufs at smem+8192); else A+B (6 gloads)
  auto stage = [&](int ks, int buf) {
    int kc = ks << 6;
    if constexpr (EPI != 4) {
      short* As = smem + buf * 12288;
      short* Bs = As + 4096;
#pragma unroll
      for (int q = 0; q < 2; ++q) {                  // A: 64 rows
        int r = q * 32 + sr;
        int c = ss ^ (r & 7);
        size_t ga = (size_t)(bm * 64 + r) * K + kc + c * 8;
        gload16(g.A + ga, &As[q * 2048 + w * 512]);
      }
#pragma unroll
      for (int q = 0; q < 4; ++q) {                  // B: 128 rows
        int r = q * 32 + sr;
        int c = ss ^ (r & 7);
        size_t gb = (size_t)(bn * 128 + r) * K + kc + c * 8;
        gload16(g.B + gb, &Bs[q * 2048 + w * 512]);
      }
    } else {
      short* Bs = smem + 8192 + buf * 8192;
#pragma unroll
      for (int q = 0; q < 4; ++q) {
        int r = q * 32 + sr;
        int c = ss ^ (r & 7);
        size_t gb = (size_t)(bn * 128 + r) * K + kc + c * 8;
        gload16(g.B + gb, &Bs[q * 2048 + w * 512]);
      }
    }
  };

  stage(0, 0);
  for (int ks = 0; ks < NK; ++ks) {
    if (ks + 1 < NK) {
      stage(ks + 1, (ks + 1) & 1);
      if constexpr (EPI == 4) asm volatile("s_waitcnt vmcnt(4)" ::: "memory");
      else                    asm volatile("s_waitcnt vmcnt(6)" ::: "memory");
    } else {
      asm volatile("s_waitcnt vmcnt(0)" ::: "memory");
    }
    // leading lgkm drain: EPI4 ks==0 needs A-build ds_writes visible;
    // otherwise free (trailing edge already drained to 0).
    asm volatile("s_waitcnt lgkmcnt(0)" ::: "memory");
    __builtin_amdgcn_sched_barrier(0);
    __builtin_amdgcn_s_barrier();

    const short* As = (EPI == 4) ? (smem + ks * 4096) : (smem + (ks & 1) * 12288);
    const short* Bs = (EPI == 4) ? (smem + 8192 + (ks & 1) * 8192) : (As + 4096);
#pragma unroll
    for (int kk = 0; kk < 2; ++kk) {
      short8 av[2], bh[4];
#pragma unroll
      for (int mi = 0; mi < 2; ++mi) {
        int row = wm + mi * 16 + l15;
        av[mi] = *(const short8*)&As[row * 64 + (((kk * 4 + l4) ^ (row & 7)) << 3)];
      }
#pragma unroll
      for (int ni = 0; ni < 4; ++ni) {
        int row = wn + ni * 16 + l15;
        bh[ni] = *(const short8*)&Bs[row * 64 + (((kk * 4 + l4) ^ (row & 7)) << 3)];
      }
#pragma unroll
      for (int mi = 0; mi < 2; ++mi)
#pragma unroll
        for (int ni = 0; ni < 4; ++ni)
          acc[mi][ni] = mf(av[mi], bh[ni], acc[mi][ni]);
    }
    asm volatile("s_waitcnt lgkmcnt(0)" ::: "memory");
    __builtin_amdgcn_sched_barrier(0);
    __builtin_amdgcn_s_barrier();
  }

  const int gm0 = bm * 64 + wm;
  const int gn0 = bn * 128 + wn;
  float wp[2][4] = {};
#pragma unroll
  for (int mi = 0; mi < 2; ++mi) {
#pragma unroll
    for (int ni = 0; ni < 4; ++ni) {
      int n = gn0 + ni * 16 + l15;
#pragma unroll
      for (int r = 0; r < 4; ++r) {
        int m = gm0 + mi * 16 + l4 * 4 + r;
        float v = acc[mi][ni][r];
        if constexpr (EPI == 0 || EPI == 4) {
          float h = fast_tanh(v + g.bias[n]);
          g.Oh[(size_t)m * UNITS + n] = f2h_bits(h);
        } else if constexpr (EPI == 1) {
          size_t idx = (size_t)m * UNITS + n;
          float h = h2f_bits(g.Hh[idx]);
          g.Oh[idx] = f2h_bits(v * (1.0f - h * h));
        } else if constexpr (EPI == 2) {
          if (n < GRAD_COLS)
            g.Og[((size_t)m * NITER + g.iter) * GRAD_COLS + n] = v;
        } else {
          float h = fast_tanh(v + g.bias[n]);
          float w4 = g.W4p[n];
          g.Oh[(size_t)m * UNITS + n] = f2h_bits((1.0f - h * h) * w4);
          wp[mi][r] += h * w4;
        }
      }
    }
  }
  if constexpr (EPI == 3) {
#pragma unroll
    for (int mi = 0; mi < 2; ++mi)
#pragma unroll
      for (int r = 0; r < 4; ++r) {
        float v = wp[mi][r];
        v += __shfl_xor(v, 1); v += __shfl_xor(v, 2);
        v += __shfl_xor(v, 4); v += __shfl_xor(v, 8);
        if (l15 == 0) {
          int m = gm0 + mi * 16 + l4 * 4 + r;
          atomicAdd(&g.Og[m], v);
        }
      }
  }
  if constexpr (EPI == 2) {
    // final iteration only: w_out[:,24] = w_acc[24] + b4
    if (g.woutp && wn == 0 && l15 == 0) {
#pragma unroll
      for (int mi = 0; mi < 2; ++mi)
#pragma unroll
        for (int r = 0; r < 4; ++r) {
          int m = gm0 + mi * 16 + l4 * 4 + r;
          g.woutp[(size_t)m * NITER + 24] = g.waccp[m] + g.b4p[0];
        }
    }
  }
}

// Chunked pairing: blocks [0,nA) run EA with id+offA; rest run EB with id-nA+offB.
template<int EA, int EB>
__global__ __launch_bounds__(256, 3)
void paired_kernel(GArgs A, GArgs B, int nA, int offA, int offB) {
  __shared__ short smem[24576];        // 48KB -> 3 blocks/CU
  int id = blockIdx.x;
  if (id < nA) gemm64<EA>(A, smem, id + offA);
  else         gemm64<EB>(B, smem, id - nA + offB);
}

template<int E>
__global__ __launch_bounds__(256, 3)
void solo_kernel(GArgs A) {
  __shared__ short smem[24576];
  gemm64<E>(A, smem, blockIdx.x);
}

// ---------------------------------------------------------------------------
extern "C" void kernel_launch(void* const* d_in, const int* in_sizes, int n_in,
                              void* d_out, int out_size, void* d_ws, size_t ws_size,
                              hipStream_t stream) {
  const float* x  = (const float*)d_in[0];
  const float* W0 = (const float*)d_in[1];
  const float* b0 = (const float*)d_in[2];
  const float* W1 = (const float*)d_in[3];
  const float* b1 = (const float*)d_in[4];
  const float* W2 = (const float*)d_in[5];
  const float* b2 = (const float*)d_in[6];
  const float* W3 = (const float*)d_in[7];
  const float* b3 = (const float*)d_in[8];
  const float* W4 = (const float*)d_in[9];
  const float* b4 = (const float*)d_in[10];

  float* w_out    = (float*)d_out;                              // (8192, 25)
  float* grad_out = (float*)d_out + (size_t)B_ROWS * NITER;     // (8192, 25, 101)

  char* p = (char*)d_ws;
  auto alloc = [&](size_t elems) { unsigned short* r = (unsigned short*)p; p += elems * 2; return r; };

  unsigned short* TW0 = alloc(512 * KPAD);
  unsigned short* TW1 = alloc(512 * 512);
  unsigned short* TW2 = alloc(512 * 512);
  unsigned short* TW3 = alloc(512 * 512);
  unsigned short* CW0 = alloc(KPAD * 512);
  unsigned short* CW1 = alloc(512 * 512);
  unsigned short* CW2 = alloc(512 * 512);
  unsigned short* CW3 = alloc(512 * 512);
  float* w_acc = (float*)p; p += (size_t)NITER * B_ROWS * 4;

  const size_t SL = (size_t)B_ROWS * UNITS;
  unsigned short *H0[2], *H1[2], *H2[2], *U3[2];
  for (int par = 0; par < 2; ++par) {
    H0[par] = alloc(SL); H1[par] = alloc(SL);
    H2[par] = alloc(SL); U3[par] = alloc(SL);
  }
  unsigned short* Ub = alloc(SL);
  unsigned short* Uc = alloc(SL);

  prep_kernel<<<1024, 256, 0, stream>>>(W0, W1, W2, W3,
      TW0, TW1, TW2, TW3, CW0, CW1, CW2, CW3, w_acc);

  // prologue: forward chain for iteration 0 (parity 0); f0 builds D on the fly
  {
    GArgs f0 = {nullptr, TW0, KPAD, b0, nullptr, H0[0], nullptr, 0, nullptr,
                x, w_out, w_acc, b4};
    GArgs f1 = {H0[0], TW1, 512, b1, nullptr, H1[0], nullptr, 0, nullptr,
                nullptr, nullptr, nullptr, nullptr};
    GArgs f2 = {H1[0], TW2, 512, b2, nullptr, H2[0], nullptr, 0, nullptr,
                nullptr, nullptr, nullptr, nullptr};
    GArgs f3 = {H2[0], TW3, 512, b3, nullptr, U3[0], w_acc, 0, W4,
                nullptr, nullptr, nullptr, nullptr};
    solo_kernel<4><<<512, 256, 0, stream>>>(f0);
    solo_kernel<0><<<512, 256, 0, stream>>>(f1);
    solo_kernel<0><<<512, 256, 0, stream>>>(f2);
    solo_kernel<3><<<512, 256, 0, stream>>>(f3);
  }

  for (int i = 0; i < NITER; ++i) {
    int pp = i & 1, q = pp ^ 1;
    bool more = (i < NITER - 1);
    bool last = (i == NITER - 1);

    GArgs bw3 = {U3[pp], CW3, 512, nullptr, H2[pp], Ub, nullptr, 0, nullptr,
                 nullptr, nullptr, nullptr, nullptr};
    GArgs bw2 = {Ub,     CW2, 512, nullptr, H1[pp], Uc, nullptr, 0, nullptr,
                 nullptr, nullptr, nullptr, nullptr};
    GArgs bw1 = {Uc,     CW1, 512, nullptr, H0[pp], Ub, nullptr, 0, nullptr,
                 nullptr, nullptr, nullptr, nullptr};
    GArgs gr0 = {Ub,     CW0, 512, nullptr, nullptr, nullptr, grad_out, i, nullptr,
                 nullptr,
                 last ? w_out : nullptr,
                 last ? (w_acc + (size_t)24 * B_ROWS) : nullptr,
                 last ? b4 : nullptr};

    if (more) {
      // f-chain for iteration i+1; f0 builds D(i+1) on the fly, writes w_out[:,i]
      GArgs f0 = {nullptr, TW0, KPAD, b0, nullptr, H0[q], nullptr, i + 1, nullptr,
                  x, w_out, w_acc + (size_t)i * B_ROWS, b4};
      GArgs f1 = {H0[q], TW1, 512, b1, nullptr, H1[q], nullptr, 0, nullptr,
                  nullptr, nullptr, nullptr, nullptr};
      GArgs f2 = {H1[q], TW2, 512, b2, nullptr, H2[q], nullptr, 0, nullptr,
                  nullptr, nullptr, nullptr, nullptr};
      GArgs f3 = {H2[q], TW3, 512, b3, nullptr, U3[q],
                  w_acc + (size_t)(i + 1) * B_ROWS, 0, W4,
                  nullptr, nullptr, nullptr, nullptr};
      // Exact-fill chunked schedule (768 = 3 blocks/CU x 256 CUs):
      // D1: bw3(512) + f0[0:256)      D2: f0[256:512) + bw2(512)
      // D3: f1(512) + bw1[0:256)      D4: bw1[256:512) + f2(512)
      // D5: gr0(128) + f3(512)
      paired_kernel<1, 4><<<768, 256, 0, stream>>>(bw3, f0, 512, 0, 0);
      paired_kernel<4, 1><<<768, 256, 0, stream>>>(f0, bw2, 256, 256, 0);
      paired_kernel<0, 1><<<768, 256, 0, stream>>>(f1, bw1, 512, 0, 0);
      paired_kernel<1, 0><<<768, 256, 0, stream>>>(bw1, f2, 256, 256, 0);
      paired_kernel<2, 3><<<640, 256, 0, stream>>>(gr0, f3, 128, 0, 0);
    } else {
      solo_kernel<1><<<512, 256, 0, stream>>>(bw3);
      solo_kernel<1><<<512, 256, 0, stream>>>(bw2);
      solo_kernel<1><<<512, 256, 0, stream>>>(bw1);
      solo_kernel<2><<<128, 256, 0, stream>>>(gr0);
    }
  }

  (void)in_sizes; (void)n_in; (void)out_size; (void)ws_size;
}